// Round 1
// baseline (935.378 us; speedup 1.0000x reference)
//
#include <hip/hip_runtime.h>
#include <math.h>

#define BB   4096
#define SEQL 168
#define CF   64
#define PREDN 96
#define KK   25
#define NLAG 11

// ws layout (floats): [0,1600) softmax conv kernels; [1600,1888) Rot unitaries;
// [2048, 2048+BB*12) quantum feats
#define WS_KER   0
#define WS_U     1600
#define WS_FEATS 2048

// ---------------------------------------------------------------- precompute
__global__ void k_pre(const float* __restrict__ decomp_w,
                      const float* __restrict__ wx,
                      const float* __restrict__ wy,
                      const float* __restrict__ wz,
                      float* __restrict__ ws)
{
    int tid = threadIdx.x;
    if (tid < 64) {
        // softmax over K for channel tid
        float v[KK]; float mx = -1e30f;
        #pragma unroll
        for (int k = 0; k < KK; ++k) { v[k] = decomp_w[tid*KK + k]; mx = fmaxf(mx, v[k]); }
        float s = 0.f;
        #pragma unroll
        for (int k = 0; k < KK; ++k) { v[k] = expf(v[k] - mx); s += v[k]; }
        float inv = 1.f / s;
        #pragma unroll
        for (int k = 0; k < KK; ++k) ws[WS_KER + tid*KK + k] = v[k]*inv;
    } else if (tid < 64 + 36) {
        // Rot(phi,theta,omega) unitaries: i = circ*12 + layer*4 + q
        int i = tid - 64;
        int circ = i / 12, r = i % 12;
        const float* w = (circ == 0) ? wx : (circ == 1 ? wy : wz);
        float phi = w[r*3+0], th = w[r*3+1], om = w[r*3+2];
        float ct = cosf(0.5f*th), st = sinf(0.5f*th);
        float po = 0.5f*(phi+om), pm = 0.5f*(phi-om);
        float cpo = cosf(po), spo = sinf(po);
        float cpm = cosf(pm), spm = sinf(pm);
        float* U = ws + WS_U + i*8;
        U[0] =  cpo*ct; U[1] = -spo*ct;   // U00 = ep*ct,        ep = exp(-i*po)
        U[2] = -cpm*st; U[3] = -spm*st;   // U01 = -em*st,       em = exp(+i*pm)
        U[4] =  cpm*st; U[5] = -spm*st;   // U10 = conj(em)*st
        U[6] =  cpo*ct; U[7] =  spo*ct;   // U11 = conj(ep)*ct
    }
}

// ---------------------------------------------------------------- quantum feats
// one thread per (batch row, circuit). 16 complex amplitudes fully unrolled in regs.
__global__ void k_quantum(const float* __restrict__ x,
                          const float* __restrict__ lagc_W,
                          const float* __restrict__ lagc_b,
                          const float* __restrict__ ws,
                          float* __restrict__ feats)
{
    int tid = blockIdx.x * blockDim.x + threadIdx.x;
    if (tid >= BB*3) return;
    int b = tid / 3, circ = tid - b*3;

    const int LAGS[NLAG] = {167,166,165,164,163,162,145,144,143,1,0};
    const float* xb = x + (size_t)b*SEQL*CF + (CF-1);   // channel 63
    float lag[NLAG];
    #pragma unroll
    for (int j = 0; j < NLAG; ++j) lag[j] = xb[LAGS[j]*CF];

    // q_in = tanh(lag @ lagc_W.T + b) * pi ; store half-angle sin/cos for RY
    float cq[4], sq[4];
    #pragma unroll
    for (int q = 0; q < 4; ++q) {
        float acc = lagc_b[q];
        #pragma unroll
        for (int j = 0; j < NLAG; ++j) acc = fmaf(lag[j], lagc_W[q*NLAG + j], acc);
        float half = 0.5f * 3.14159265358979323846f * tanhf(acc);
        cq[q] = cosf(half); sq[q] = sinf(half);
    }

    float sr[16], si[16];
    #pragma unroll
    for (int i = 0; i < 16; ++i) { sr[i] = 0.f; si[i] = 0.f; }
    sr[0] = 1.f;

    const float* Ub = ws + WS_U + circ*96;

    for (int layer = 0; layer < 3; ++layer) {
        // RY(q_in[q]) on qubit q  (qubit q <-> bit 3-q of flat index)
        #pragma unroll
        for (int q = 0; q < 4; ++q) {
            int msk = 1 << (3-q);
            float cc = cq[q], ss = sq[q];
            #pragma unroll
            for (int idx = 0; idx < 16; ++idx) {
                if (idx & msk) continue;
                int j = idx | msk;
                float a0r = sr[idx], a0i = si[idx];
                float a1r = sr[j],   a1i = si[j];
                sr[idx] = cc*a0r - ss*a1r;  si[idx] = cc*a0i - ss*a1i;
                sr[j]   = ss*a0r + cc*a1r;  si[j]   = ss*a0i + cc*a1i;
            }
        }
        // Rot (complex 2x2)
        #pragma unroll
        for (int q = 0; q < 4; ++q) {
            const float* U = Ub + (layer*4 + q)*8;
            float u00r=U[0],u00i=U[1],u01r=U[2],u01i=U[3];
            float u10r=U[4],u10i=U[5],u11r=U[6],u11i=U[7];
            int msk = 1 << (3-q);
            #pragma unroll
            for (int idx = 0; idx < 16; ++idx) {
                if (idx & msk) continue;
                int j = idx | msk;
                float a0r = sr[idx], a0i = si[idx];
                float a1r = sr[j],   a1i = si[j];
                sr[idx] = u00r*a0r - u00i*a0i + u01r*a1r - u01i*a1i;
                si[idx] = u00r*a0i + u00i*a0r + u01r*a1i + u01i*a1r;
                sr[j]   = u10r*a0r - u10i*a0i + u11r*a1r - u11i*a1i;
                si[j]   = u10r*a0i + u10i*a0r + u11r*a1i + u11i*a1r;
            }
        }
        // CNOT ring: control q, target (q+1)%4
        #pragma unroll
        for (int q = 0; q < 4; ++q) {
            int t = (q+1) & 3;
            int cm = 1 << (3-q), tm = 1 << (3-t);
            #pragma unroll
            for (int idx = 0; idx < 16; ++idx) {
                if (!(idx & cm) || (idx & tm)) continue;
                int j = idx | tm;
                float tr = sr[idx]; sr[idx] = sr[j]; sr[j] = tr;
                float ti = si[idx]; si[idx] = si[j]; si[j] = ti;
            }
        }
    }

    // expectation values for this circuit's Pauli (0:X, 1:Y, 2:Z)
    #pragma unroll
    for (int q = 0; q < 4; ++q) {
        int msk = 1 << (3-q);
        float v = 0.f;
        if (circ == 0) {
            #pragma unroll
            for (int idx = 0; idx < 16; ++idx) {
                if (idx & msk) continue;
                int j = idx | msk;
                v += sr[idx]*sr[j] + si[idx]*si[j];     // Re(conj(a0)*a1)
            }
            v *= 2.f;
        } else if (circ == 1) {
            #pragma unroll
            for (int idx = 0; idx < 16; ++idx) {
                if (idx & msk) continue;
                int j = idx | msk;
                v += sr[idx]*si[j] - si[idx]*sr[j];     // Im(conj(a0)*a1)
            }
            v *= 2.f;
        } else {
            #pragma unroll
            for (int idx = 0; idx < 16; ++idx) {
                if (idx & msk) continue;
                int j = idx | msk;
                v += sr[idx]*sr[idx] + si[idx]*si[idx]
                   - sr[j]*sr[j]     - si[j]*si[j];
            }
        }
        feats[b*12 + circ*4 + q] = v;
    }
}

// ---------------------------------------------------------------- main fused kernel
// one block per batch row. LDS: conv output ts (43KB) + per-p scale factors.
__launch_bounds__(256, 3)
__global__ void k_main(const float* __restrict__ x,
                       const float* __restrict__ ws,      // ker + feats
                       const float* __restrict__ sW,      // seas_W  [96][168]
                       const float* __restrict__ tW,      // trend_W [96][168]
                       const float* __restrict__ seas_b,
                       const float* __restrict__ trend_b,
                       const float* __restrict__ roW1,
                       const float* __restrict__ rob1,
                       const float* __restrict__ roW2,
                       const float* __restrict__ rob2,
                       const float* __restrict__ alpha,
                       float* __restrict__ out)
{
    __shared__ float ts[SEQL*CF];
    __shared__ float fs[PREDN];
    __shared__ float cb[PREDN];

    int b = blockIdx.x;
    int tid = threadIdx.x;
    const float* xb = x + (size_t)b*SEQL*CF;

    float a_sig = 1.f / (1.f + expf(-alpha[0]));
    float oma   = 1.f - a_sig;

    // readout MLP -> per-p scale fs[p] = a*(1+mod[b,p]) and bias cb[p]
    if (tid < PREDN) {
        const float* f = ws + WS_FEATS + b*12;
        float h[12];
        #pragma unroll
        for (int i = 0; i < 12; ++i) {
            float acc = rob1[i];
            #pragma unroll
            for (int j = 0; j < 12; ++j) acc = fmaf(roW1[i*12+j], f[j], acc);
            h[i] = fmaxf(acc, 0.f);
        }
        float acc = rob2[tid];
        #pragma unroll
        for (int i = 0; i < 12; ++i) acc = fmaf(roW2[tid*12+i], h[i], acc);
        float m   = tanhf(acc);
        float fsv = a_sig * (1.f + m);
        fs[tid] = fsv;
        cb[tid] = fsv*seas_b[tid] + oma*trend_b[tid];
    }

    // depthwise conv (edge-padded, cross-correlation) -> ts in LDS
    {
        int c2 = tid & 31, seg = tid >> 5;    // 2 channels/thread, 8 segs x 21 rows
        int c0 = c2*2;
        float k0[KK], k1[KK];
        #pragma unroll
        for (int k = 0; k < KK; ++k) {
            k0[k] = ws[WS_KER + c0*KK + k];
            k1[k] = ws[WS_KER + (c0+1)*KK + k];
        }
        int l0 = seg*21;
        for (int l = l0; l < l0+21; ++l) {
            float t0 = 0.f, t1 = 0.f;
            #pragma unroll
            for (int k = 0; k < KK; ++k) {
                int lk = l + k - 12;
                lk = lk < 0 ? 0 : (lk > SEQL-1 ? SEQL-1 : lk);
                float2 xv = *(const float2*)(xb + lk*CF + c0);
                t0 = fmaf(k0[k], xv.x, t0);
                t1 = fmaf(k1[k], xv.y, t1);
            }
            ts[l*CF + c0]     = t0;
            ts[l*CF + c0 + 1] = t1;
        }
    }
    __syncthreads();

    // dual GEMM over K=168: seasonal=(x-t) @ seas_W.T and t @ trend_W.T
    // lane = channel c; p is wave-uniform -> weight loads become scalar s_loads
    int c  = tid & 63;
    int pg = __builtin_amdgcn_readfirstlane(tid >> 6);   // 0..3, uniform per wave
    float accS[24], accT[24];
    #pragma unroll
    for (int j = 0; j < 24; ++j) { accS[j] = 0.f; accT[j] = 0.f; }

    #pragma unroll 4
    for (int l = 0; l < SEQL; ++l) {
        float xv = xb[l*CF + c];
        float tv = ts[l*CF + c];
        float sv = xv - tv;
        #pragma unroll
        for (int j = 0; j < 24; ++j) {
            int p = pg + (j << 2);
            accS[j] = fmaf(sv, sW[p*SEQL + l], accS[j]);
            accT[j] = fmaf(tv, tW[p*SEQL + l], accT[j]);
        }
    }

    float* og = out + (size_t)b*PREDN*CF;
    #pragma unroll
    for (int j = 0; j < 24; ++j) {
        int p = pg + (j << 2);
        og[p*CF + c] = fs[p]*accS[j] + oma*accT[j] + cb[p];
    }
}

// ---------------------------------------------------------------- launch
extern "C" void kernel_launch(void* const* d_in, const int* in_sizes, int n_in,
                              void* d_out, int out_size, void* d_ws, size_t ws_size,
                              hipStream_t stream)
{
    const float* x        = (const float*)d_in[0];
    const float* decomp_w = (const float*)d_in[1];
    const float* trend_W  = (const float*)d_in[2];
    const float* trend_b  = (const float*)d_in[3];
    const float* seas_W   = (const float*)d_in[4];
    const float* seas_b   = (const float*)d_in[5];
    const float* lagc_W   = (const float*)d_in[6];
    const float* lagc_b   = (const float*)d_in[7];
    const float* res_wx   = (const float*)d_in[8];
    const float* res_wy   = (const float*)d_in[9];
    const float* res_wz   = (const float*)d_in[10];
    const float* ro_W1    = (const float*)d_in[11];
    const float* ro_b1    = (const float*)d_in[12];
    const float* ro_W2    = (const float*)d_in[13];
    const float* ro_b2    = (const float*)d_in[14];
    const float* alpha    = (const float*)d_in[15];
    float* out = (float*)d_out;
    float* ws  = (float*)d_ws;

    k_pre<<<1, 128, 0, stream>>>(decomp_w, res_wx, res_wy, res_wz, ws);
    k_quantum<<<(BB*3 + 255)/256, 256, 0, stream>>>(x, lagc_W, lagc_b, ws, ws + WS_FEATS);
    k_main<<<BB, 256, 0, stream>>>(x, ws, seas_W, trend_W, seas_b, trend_b,
                                   ro_W1, ro_b1, ro_W2, ro_b2, alpha, out);
}

// Round 2
// 864.880 us; speedup vs baseline: 1.0815x; 1.0815x over previous
//
#include <hip/hip_runtime.h>
#include <math.h>

#define BB   4096
#define SEQL 168
#define CF   64
#define PREDN 96
#define KK   25
#define NLAG 11

// ws layout (float offsets):
// [0,1600)        softmax conv kernels (fp32, [c][25])
// [1600,1888)     Rot unitaries (36 x 8)
// [2048, 51200)   quantum feats (4096 x 12)
// [51200, 69632)  swizzled bf16 weights (36864 u16): [mat][nt6][ks6][lane64][j8]
#define WS_KER   0
#define WS_U     1600
#define WS_FEATS 2048
#define WS_SWZ   51200

typedef __attribute__((ext_vector_type(8))) short short8;
typedef __attribute__((ext_vector_type(4))) float f32x4;

__device__ __forceinline__ unsigned short f2bf(float f) {
    unsigned int u = __float_as_uint(f);
    u = (u + 0x7FFFu + ((u >> 16) & 1u)) >> 16;   // RNE
    return (unsigned short)u;
}

// ---------------------------------------------------------------- precompute
__global__ void k_pre(const float* __restrict__ decomp_w,
                      const float* __restrict__ wx,
                      const float* __restrict__ wy,
                      const float* __restrict__ wz,
                      const float* __restrict__ sW,
                      const float* __restrict__ tW,
                      const float* __restrict__ alpha,
                      float* __restrict__ ws)
{
    int tid = threadIdx.x;
    if (tid < 64) {
        float v[KK]; float mx = -1e30f;
        #pragma unroll
        for (int k = 0; k < KK; ++k) { v[k] = decomp_w[tid*KK + k]; mx = fmaxf(mx, v[k]); }
        float s = 0.f;
        #pragma unroll
        for (int k = 0; k < KK; ++k) { v[k] = expf(v[k] - mx); s += v[k]; }
        float inv = 1.f / s;
        #pragma unroll
        for (int k = 0; k < KK; ++k) ws[WS_KER + tid*KK + k] = v[k]*inv;
    } else if (tid < 64 + 36) {
        int i = tid - 64;
        int circ = i / 12, r = i % 12;
        const float* w = (circ == 0) ? wx : (circ == 1 ? wy : wz);
        float phi = w[r*3+0], th = w[r*3+1], om = w[r*3+2];
        float ct = cosf(0.5f*th), st = sinf(0.5f*th);
        float po = 0.5f*(phi+om), pm = 0.5f*(phi-om);
        float cpo = cosf(po), spo = sinf(po);
        float cpm = cosf(pm), spm = sinf(pm);
        float* U = ws + WS_U + i*8;
        U[0] =  cpo*ct; U[1] = -spo*ct;
        U[2] = -cpm*st; U[3] = -spm*st;
        U[4] =  cpm*st; U[5] = -spm*st;
        U[6] =  cpo*ct; U[7] =  spo*ct;
    }

    // swizzle weights into MFMA B-fragment layout, bf16.
    // mat 0 = seas_W (unscaled); mat 1 = trend_W * oma (folded).
    float oma = 1.f - 1.f/(1.f + expf(-alpha[0]));
    unsigned short* wsw = (unsigned short*)(ws + WS_SWZ);
    for (int idx = tid; idx < 2*6*6*64*8; idx += 256) {
        int j    = idx & 7;
        int lane = (idx >> 3) & 63;
        int rem  = idx >> 9;
        int ks   = rem % 6;
        int nt   = (rem / 6) % 6;
        int mat  = rem / 36;
        int p = nt*16 + (lane & 15);
        int l = ks*32 + ((lane >> 4) & 3)*8 + j;
        float v = 0.f;
        if (l < SEQL) v = mat ? oma * tW[p*SEQL + l] : sW[p*SEQL + l];
        wsw[idx] = f2bf(v);
    }
}

// ---------------------------------------------------------------- quantum feats
__global__ void k_quantum(const float* __restrict__ x,
                          const float* __restrict__ lagc_W,
                          const float* __restrict__ lagc_b,
                          const float* __restrict__ ws,
                          float* __restrict__ feats)
{
    int tid = blockIdx.x * blockDim.x + threadIdx.x;
    if (tid >= BB*3) return;
    int b = tid / 3, circ = tid - b*3;

    const int LAGS[NLAG] = {167,166,165,164,163,162,145,144,143,1,0};
    const float* xb = x + (size_t)b*SEQL*CF + (CF-1);
    float lag[NLAG];
    #pragma unroll
    for (int j = 0; j < NLAG; ++j) lag[j] = xb[LAGS[j]*CF];

    float cq[4], sq[4];
    #pragma unroll
    for (int q = 0; q < 4; ++q) {
        float acc = lagc_b[q];
        #pragma unroll
        for (int j = 0; j < NLAG; ++j) acc = fmaf(lag[j], lagc_W[q*NLAG + j], acc);
        float half = 0.5f * 3.14159265358979323846f * tanhf(acc);
        cq[q] = cosf(half); sq[q] = sinf(half);
    }

    float sr[16], si[16];
    #pragma unroll
    for (int i = 0; i < 16; ++i) { sr[i] = 0.f; si[i] = 0.f; }
    sr[0] = 1.f;

    const float* Ub = ws + WS_U + circ*96;

    for (int layer = 0; layer < 3; ++layer) {
        #pragma unroll
        for (int q = 0; q < 4; ++q) {
            int msk = 1 << (3-q);
            float cc = cq[q], ss = sq[q];
            #pragma unroll
            for (int idx = 0; idx < 16; ++idx) {
                if (idx & msk) continue;
                int j = idx | msk;
                float a0r = sr[idx], a0i = si[idx];
                float a1r = sr[j],   a1i = si[j];
                sr[idx] = cc*a0r - ss*a1r;  si[idx] = cc*a0i - ss*a1i;
                sr[j]   = ss*a0r + cc*a1r;  si[j]   = ss*a0i + cc*a1i;
            }
        }
        #pragma unroll
        for (int q = 0; q < 4; ++q) {
            const float* U = Ub + (layer*4 + q)*8;
            float u00r=U[0],u00i=U[1],u01r=U[2],u01i=U[3];
            float u10r=U[4],u10i=U[5],u11r=U[6],u11i=U[7];
            int msk = 1 << (3-q);
            #pragma unroll
            for (int idx = 0; idx < 16; ++idx) {
                if (idx & msk) continue;
                int j = idx | msk;
                float a0r = sr[idx], a0i = si[idx];
                float a1r = sr[j],   a1i = si[j];
                sr[idx] = u00r*a0r - u00i*a0i + u01r*a1r - u01i*a1i;
                si[idx] = u00r*a0i + u00i*a0r + u01r*a1i + u01i*a1r;
                sr[j]   = u10r*a0r - u10i*a0i + u11r*a1r - u11i*a1i;
                si[j]   = u10r*a0i + u10i*a0r + u11r*a1i + u11i*a1r;
            }
        }
        #pragma unroll
        for (int q = 0; q < 4; ++q) {
            int t = (q+1) & 3;
            int cm = 1 << (3-q), tm = 1 << (3-t);
            #pragma unroll
            for (int idx = 0; idx < 16; ++idx) {
                if (!(idx & cm) || (idx & tm)) continue;
                int j = idx | tm;
                float tr = sr[idx]; sr[idx] = sr[j]; sr[j] = tr;
                float ti = si[idx]; si[idx] = si[j]; si[j] = ti;
            }
        }
    }

    #pragma unroll
    for (int q = 0; q < 4; ++q) {
        int msk = 1 << (3-q);
        float v = 0.f;
        if (circ == 0) {
            #pragma unroll
            for (int idx = 0; idx < 16; ++idx) {
                if (idx & msk) continue;
                int j = idx | msk;
                v += sr[idx]*sr[j] + si[idx]*si[j];
            }
            v *= 2.f;
        } else if (circ == 1) {
            #pragma unroll
            for (int idx = 0; idx < 16; ++idx) {
                if (idx & msk) continue;
                int j = idx | msk;
                v += sr[idx]*si[j] - si[idx]*sr[j];
            }
            v *= 2.f;
        } else {
            #pragma unroll
            for (int idx = 0; idx < 16; ++idx) {
                if (idx & msk) continue;
                int j = idx | msk;
                v += sr[idx]*sr[idx] + si[idx]*si[idx]
                   - sr[j]*sr[j]     - si[j]*si[j];
            }
        }
        feats[b*12 + circ*4 + q] = v;
    }
}

// ---------------------------------------------------------------- fused conv+GEMM (MFMA)
// 1 block = 1 batch row, 128 threads = 2 waves. Wave w covers channels
// [w*32, w*32+32) as two 16-row MFMA m-tiles. Conv outputs land directly in
// A-fragment register layout (m=c: lane&15; k=l: (lane>>4)*8+j) — no LDS.
__launch_bounds__(128, 3)
__global__ void k_gemm(const float* __restrict__ x,
                       const float* __restrict__ ws,
                       const float* __restrict__ seas_b,
                       const float* __restrict__ trend_b,
                       const float* __restrict__ roW1,
                       const float* __restrict__ rob1,
                       const float* __restrict__ roW2,
                       const float* __restrict__ rob2,
                       const float* __restrict__ alpha,
                       float* __restrict__ out)
{
    __shared__ float fsL[PREDN];
    __shared__ float cbL[PREDN];

    int b = blockIdx.x;
    int tid = threadIdx.x;

    float a_sig = 1.f / (1.f + expf(-alpha[0]));
    float oma   = 1.f - a_sig;

    // readout MLP -> fs[p], cb[p]
    if (tid < PREDN) {
        const float* f = ws + WS_FEATS + b*12;
        float h[12];
        #pragma unroll
        for (int i = 0; i < 12; ++i) {
            float acc = rob1[i];
            #pragma unroll
            for (int j = 0; j < 12; ++j) acc = fmaf(roW1[i*12+j], f[j], acc);
            h[i] = fmaxf(acc, 0.f);
        }
        float acc = rob2[tid];
        #pragma unroll
        for (int i = 0; i < 12; ++i) acc = fmaf(roW2[tid*12+i], h[i], acc);
        float m   = tanhf(acc);
        float fsv = a_sig * (1.f + m);
        fsL[tid] = fsv;
        cbL[tid] = fsv*seas_b[tid] + oma*trend_b[tid];
    }
    __syncthreads();

    int lane = tid & 63;
    int cw   = tid >> 6;          // which 32-channel half
    int mrow = lane & 15;         // m within tile = c within 16
    int q    = lane >> 4;         // k-quad

    const float* xb = x + (size_t)b*SEQL*CF;

    // ---- conv directly into A fragments (bf16), T and S = x - T ----
    short8 At[2][6], As[2][6];
    #pragma unroll
    for (int ct = 0; ct < 2; ++ct) {
        int c = (cw<<5) + (ct<<4) + mrow;
        float cf[KK];
        #pragma unroll
        for (int k = 0; k < KK; ++k) cf[k] = ws[WS_KER + c*KK + k];
        const float* xc = xb + c;
        #pragma unroll
        for (int ks = 0; ks < 6; ++ks) {
            int l0 = ks*32 + q*8;                 // first output l of 8-group
            float xw[32];
            #pragma unroll
            for (int t = 0; t < 32; ++t) {
                int ix = l0 - 12 + t;
                ix = ix < 0 ? 0 : (ix > SEQL-1 ? SEQL-1 : ix);
                xw[t] = xc[ix*CF];
            }
            short8 aT, aS;
            #pragma unroll
            for (int j = 0; j < 8; ++j) {
                float tv = 0.f;
                #pragma unroll
                for (int k = 0; k < KK; ++k) tv = fmaf(cf[k], xw[j+k], tv);
                float sv = xw[j+12] - tv;
                bool pad = (l0 + j) > (SEQL-1);
                tv = pad ? 0.f : tv;
                sv = pad ? 0.f : sv;
                aT[j] = (short)f2bf(tv);
                aS[j] = (short)f2bf(sv);
            }
            At[ct][ks] = aT;
            As[ct][ks] = aS;
        }
    }

    // ---- MFMA over p-tiles; B frags from pre-swizzled global (L2-hot) ----
    const unsigned short* wsw = (const unsigned short*)(ws + WS_SWZ);
    for (int nt = 0; nt < 6; ++nt) {
        f32x4 aS0 = {0.f,0.f,0.f,0.f}, aS1 = {0.f,0.f,0.f,0.f};
        f32x4 aT0 = {0.f,0.f,0.f,0.f}, aT1 = {0.f,0.f,0.f,0.f};
        #pragma unroll
        for (int ks = 0; ks < 6; ++ks) {
            short8 Bs = *(const short8*)(wsw + (((0*6 + nt)*6 + ks)*64 + lane)*8);
            short8 Bt = *(const short8*)(wsw + (((1*6 + nt)*6 + ks)*64 + lane)*8);
            aS0 = __builtin_amdgcn_mfma_f32_16x16x32_bf16(As[0][ks], Bs, aS0, 0, 0, 0);
            aS1 = __builtin_amdgcn_mfma_f32_16x16x32_bf16(As[1][ks], Bs, aS1, 0, 0, 0);
            aT0 = __builtin_amdgcn_mfma_f32_16x16x32_bf16(At[0][ks], Bt, aT0, 0, 0, 0);
            aT1 = __builtin_amdgcn_mfma_f32_16x16x32_bf16(At[1][ks], Bt, aT1, 0, 0, 0);
        }
        int p = nt*16 + mrow;                     // C/D: col = lane&15 = p
        float fsv = fsL[p];
        float cbv = cbL[p];
        // C/D: row = q*4 + reg = c within tile  (trend already oma-scaled)
        float* og = out + (size_t)b*PREDN*CF + p*CF + (cw<<5) + (q<<2);
        f32x4 r0, r1;
        #pragma unroll
        for (int r = 0; r < 4; ++r) {
            r0[r] = fmaf(fsv, aS0[r], aT0[r] + cbv);
            r1[r] = fmaf(fsv, aS1[r], aT1[r] + cbv);
        }
        *(f32x4*)(og)      = r0;
        *(f32x4*)(og + 16) = r1;
    }
}

// ---------------------------------------------------------------- launch
extern "C" void kernel_launch(void* const* d_in, const int* in_sizes, int n_in,
                              void* d_out, int out_size, void* d_ws, size_t ws_size,
                              hipStream_t stream)
{
    const float* x        = (const float*)d_in[0];
    const float* decomp_w = (const float*)d_in[1];
    const float* trend_W  = (const float*)d_in[2];
    const float* trend_b  = (const float*)d_in[3];
    const float* seas_W   = (const float*)d_in[4];
    const float* seas_b   = (const float*)d_in[5];
    const float* lagc_W   = (const float*)d_in[6];
    const float* lagc_b   = (const float*)d_in[7];
    const float* res_wx   = (const float*)d_in[8];
    const float* res_wy   = (const float*)d_in[9];
    const float* res_wz   = (const float*)d_in[10];
    const float* ro_W1    = (const float*)d_in[11];
    const float* ro_b1    = (const float*)d_in[12];
    const float* ro_W2    = (const float*)d_in[13];
    const float* ro_b2    = (const float*)d_in[14];
    const float* alpha    = (const float*)d_in[15];
    float* out = (float*)d_out;
    float* ws  = (float*)d_ws;

    k_pre<<<1, 256, 0, stream>>>(decomp_w, res_wx, res_wy, res_wz,
                                 seas_W, trend_W, alpha, ws);
    k_quantum<<<(BB*3 + 255)/256, 256, 0, stream>>>(x, lagc_W, lagc_b, ws, ws + WS_FEATS);
    k_gemm<<<BB, 128, 0, stream>>>(x, ws, seas_b, trend_b,
                                   ro_W1, ro_b1, ro_W2, ro_b2, alpha, out);
}

// Round 3
// 743.916 us; speedup vs baseline: 1.2574x; 1.1626x over previous
//
#include <hip/hip_runtime.h>
#include <math.h>

#define BB   4096
#define SEQL 168
#define CF   64
#define PREDN 96
#define KK   25
#define NLAG 11

// ws layout (float offsets):
// [0,1600)        softmax conv kernels (fp32, [c][25])
// [1600,1888)     Rot unitaries (36 x 8)
// [2048, 51200)   quantum feats (4096 x 12)
// [51200, 69632)  swizzled bf16 weights (36864 u16): [mat][nt6][ks6][lane64][j8]
#define WS_KER   0
#define WS_U     1600
#define WS_FEATS 2048
#define WS_SWZ   51200

typedef __attribute__((ext_vector_type(8))) short short8;
typedef __attribute__((ext_vector_type(4))) float f32x4;

__device__ __forceinline__ unsigned short f2bf(float f) {
    unsigned int u = __float_as_uint(f);
    u = (u + 0x7FFFu + ((u >> 16) & 1u)) >> 16;   // RNE
    return (unsigned short)u;
}

// ---------------------------------------------------------------- precompute (small)
__global__ void k_pre(const float* __restrict__ decomp_w,
                      const float* __restrict__ wx,
                      const float* __restrict__ wy,
                      const float* __restrict__ wz,
                      float* __restrict__ ws)
{
    int tid = threadIdx.x;
    if (tid < 64) {
        float v[KK]; float mx = -1e30f;
        #pragma unroll
        for (int k = 0; k < KK; ++k) { v[k] = decomp_w[tid*KK + k]; mx = fmaxf(mx, v[k]); }
        float s = 0.f;
        #pragma unroll
        for (int k = 0; k < KK; ++k) { v[k] = expf(v[k] - mx); s += v[k]; }
        float inv = 1.f / s;
        #pragma unroll
        for (int k = 0; k < KK; ++k) ws[WS_KER + tid*KK + k] = v[k]*inv;
    } else if (tid < 64 + 36) {
        int i = tid - 64;
        int circ = i / 12, r = i % 12;
        const float* w = (circ == 0) ? wx : (circ == 1 ? wy : wz);
        float phi = w[r*3+0], th = w[r*3+1], om = w[r*3+2];
        float ct = cosf(0.5f*th), st = sinf(0.5f*th);
        float po = 0.5f*(phi+om), pm = 0.5f*(phi-om);
        float cpo = cosf(po), spo = sinf(po);
        float cpm = cosf(pm), spm = sinf(pm);
        float* U = ws + WS_U + i*8;
        U[0] =  cpo*ct; U[1] = -spo*ct;
        U[2] = -cpm*st; U[3] = -spm*st;
        U[4] =  cpm*st; U[5] = -spm*st;
        U[6] =  cpo*ct; U[7] =  spo*ct;
    }
}

// ---------------------------------------------------------------- weight swizzle (parallel)
// mat 0 = seas_W (unscaled); mat 1 = trend_W * oma (folded). B-fragment layout.
__global__ void k_swz(const float* __restrict__ sW,
                      const float* __restrict__ tW,
                      const float* __restrict__ alpha,
                      float* __restrict__ ws)
{
    int idx = blockIdx.x * blockDim.x + threadIdx.x;
    if (idx >= 2*6*6*64*8) return;
    float oma = 1.f - 1.f/(1.f + expf(-alpha[0]));
    unsigned short* wsw = (unsigned short*)(ws + WS_SWZ);
    int j    = idx & 7;
    int lane = (idx >> 3) & 63;
    int rem  = idx >> 9;
    int ks   = rem % 6;
    int nt   = (rem / 6) % 6;
    int mat  = rem / 36;
    int p = nt*16 + (lane & 15);
    int l = ks*32 + ((lane >> 4) & 3)*8 + j;
    float v = 0.f;
    if (l < SEQL) v = mat ? oma * tW[p*SEQL + l] : sW[p*SEQL + l];
    wsw[idx] = f2bf(v);
}

// ---------------------------------------------------------------- quantum feats
__global__ void k_quantum(const float* __restrict__ x,
                          const float* __restrict__ lagc_W,
                          const float* __restrict__ lagc_b,
                          const float* __restrict__ ws,
                          float* __restrict__ feats)
{
    int tid = blockIdx.x * blockDim.x + threadIdx.x;
    if (tid >= BB*3) return;
    int b = tid / 3, circ = tid - b*3;

    const int LAGS[NLAG] = {167,166,165,164,163,162,145,144,143,1,0};
    const float* xb = x + (size_t)b*SEQL*CF + (CF-1);
    float lag[NLAG];
    #pragma unroll
    for (int j = 0; j < NLAG; ++j) lag[j] = xb[LAGS[j]*CF];

    float cq[4], sq[4];
    #pragma unroll
    for (int q = 0; q < 4; ++q) {
        float acc = lagc_b[q];
        #pragma unroll
        for (int j = 0; j < NLAG; ++j) acc = fmaf(lag[j], lagc_W[q*NLAG + j], acc);
        float half = 0.5f * 3.14159265358979323846f * tanhf(acc);
        cq[q] = cosf(half); sq[q] = sinf(half);
    }

    float sr[16], si[16];
    #pragma unroll
    for (int i = 0; i < 16; ++i) { sr[i] = 0.f; si[i] = 0.f; }
    sr[0] = 1.f;

    const float* Ub = ws + WS_U + circ*96;

    for (int layer = 0; layer < 3; ++layer) {
        #pragma unroll
        for (int q = 0; q < 4; ++q) {
            int msk = 1 << (3-q);
            float cc = cq[q], ss = sq[q];
            #pragma unroll
            for (int idx = 0; idx < 16; ++idx) {
                if (idx & msk) continue;
                int j = idx | msk;
                float a0r = sr[idx], a0i = si[idx];
                float a1r = sr[j],   a1i = si[j];
                sr[idx] = cc*a0r - ss*a1r;  si[idx] = cc*a0i - ss*a1i;
                sr[j]   = ss*a0r + cc*a1r;  si[j]   = ss*a0i + cc*a1i;
            }
        }
        #pragma unroll
        for (int q = 0; q < 4; ++q) {
            const float* U = Ub + (layer*4 + q)*8;
            float u00r=U[0],u00i=U[1],u01r=U[2],u01i=U[3];
            float u10r=U[4],u10i=U[5],u11r=U[6],u11i=U[7];
            int msk = 1 << (3-q);
            #pragma unroll
            for (int idx = 0; idx < 16; ++idx) {
                if (idx & msk) continue;
                int j = idx | msk;
                float a0r = sr[idx], a0i = si[idx];
                float a1r = sr[j],   a1i = si[j];
                sr[idx] = u00r*a0r - u00i*a0i + u01r*a1r - u01i*a1i;
                si[idx] = u00r*a0i + u00i*a0r + u01r*a1i + u01i*a1r;
                sr[j]   = u10r*a0r - u10i*a0i + u11r*a1r - u11i*a1i;
                si[j]   = u10r*a0i + u10i*a0r + u11r*a1i + u11i*a1r;
            }
        }
        #pragma unroll
        for (int q = 0; q < 4; ++q) {
            int t = (q+1) & 3;
            int cm = 1 << (3-q), tm = 1 << (3-t);
            #pragma unroll
            for (int idx = 0; idx < 16; ++idx) {
                if (!(idx & cm) || (idx & tm)) continue;
                int j = idx | tm;
                float tr = sr[idx]; sr[idx] = sr[j]; sr[j] = tr;
                float ti = si[idx]; si[idx] = si[j]; si[j] = ti;
            }
        }
    }

    #pragma unroll
    for (int q = 0; q < 4; ++q) {
        int msk = 1 << (3-q);
        float v = 0.f;
        if (circ == 0) {
            #pragma unroll
            for (int idx = 0; idx < 16; ++idx) {
                if (idx & msk) continue;
                int j = idx | msk;
                v += sr[idx]*sr[j] + si[idx]*si[j];
            }
            v *= 2.f;
        } else if (circ == 1) {
            #pragma unroll
            for (int idx = 0; idx < 16; ++idx) {
                if (idx & msk) continue;
                int j = idx | msk;
                v += sr[idx]*si[j] - si[idx]*sr[j];
            }
            v *= 2.f;
        } else {
            #pragma unroll
            for (int idx = 0; idx < 16; ++idx) {
                if (idx & msk) continue;
                int j = idx | msk;
                v += sr[idx]*sr[idx] + si[idx]*si[idx]
                   - sr[j]*sr[j]     - si[j]*si[j];
            }
        }
        feats[b*12 + circ*4 + q] = v;
    }
}

// ---------------------------------------------------------------- fused conv+GEMM (MFMA)
// 1 block = 1 batch row, 128 threads = 2 waves. ct (16-channel tile) is the
// OUTER loop so peak live state = 6-nt accumulators (48 VGPRs) + one ks-slice
// of A fragments — fits the register file with no scratch spill.
__launch_bounds__(128, 3)
__global__ void k_gemm(const float* __restrict__ x,
                       const float* __restrict__ ws,
                       const float* __restrict__ seas_b,
                       const float* __restrict__ trend_b,
                       const float* __restrict__ roW1,
                       const float* __restrict__ rob1,
                       const float* __restrict__ roW2,
                       const float* __restrict__ rob2,
                       const float* __restrict__ alpha,
                       float* __restrict__ out)
{
    __shared__ float fsL[PREDN];
    __shared__ float cbL[PREDN];

    int b = blockIdx.x;
    int tid = threadIdx.x;

    float a_sig = 1.f / (1.f + expf(-alpha[0]));
    float oma   = 1.f - a_sig;

    // readout MLP -> fs[p], cb[p]
    if (tid < PREDN) {
        const float* f = ws + WS_FEATS + b*12;
        float h[12];
        #pragma unroll
        for (int i = 0; i < 12; ++i) {
            float acc = rob1[i];
            #pragma unroll
            for (int j = 0; j < 12; ++j) acc = fmaf(roW1[i*12+j], f[j], acc);
            h[i] = fmaxf(acc, 0.f);
        }
        float acc = rob2[tid];
        #pragma unroll
        for (int i = 0; i < 12; ++i) acc = fmaf(roW2[tid*12+i], h[i], acc);
        float m   = tanhf(acc);
        float fsv = a_sig * (1.f + m);
        fsL[tid] = fsv;
        cbL[tid] = fsv*seas_b[tid] + oma*trend_b[tid];
    }
    __syncthreads();

    int lane = tid & 63;
    int cw   = tid >> 6;          // which 32-channel half
    int mrow = lane & 15;         // m within tile = c within 16
    int q    = lane >> 4;         // k-quad

    const float* xb = x + (size_t)b*SEQL*CF;
    const unsigned short* wsw = (const unsigned short*)(ws + WS_SWZ);

    for (int ct = 0; ct < 2; ++ct) {
        int c = (cw<<5) + (ct<<4) + mrow;
        float cf[KK];
        #pragma unroll
        for (int k = 0; k < KK; ++k) cf[k] = ws[WS_KER + c*KK + k];
        const float* xc = xb + c;

        f32x4 accS[6], accT[6];
        #pragma unroll
        for (int nt = 0; nt < 6; ++nt) {
            accS[nt] = (f32x4){0.f,0.f,0.f,0.f};
            accT[nt] = (f32x4){0.f,0.f,0.f,0.f};
        }

        for (int ks = 0; ks < 6; ++ks) {
            int l0 = ks*32 + q*8;
            float xw[32];
            #pragma unroll
            for (int t = 0; t < 32; ++t) {
                int ix = l0 - 12 + t;
                ix = ix < 0 ? 0 : (ix > SEQL-1 ? SEQL-1 : ix);
                xw[t] = xc[ix*CF];
            }
            short8 aT, aS;
            #pragma unroll
            for (int j = 0; j < 8; ++j) {
                float tv = 0.f;
                #pragma unroll
                for (int k = 0; k < KK; ++k) tv = fmaf(cf[k], xw[j+k], tv);
                float sv = xw[j+12] - tv;
                bool pad = (l0 + j) > (SEQL-1);
                tv = pad ? 0.f : tv;
                sv = pad ? 0.f : sv;
                aT[j] = (short)f2bf(tv);
                aS[j] = (short)f2bf(sv);
            }
            #pragma unroll
            for (int nt = 0; nt < 6; ++nt) {
                short8 Bs = *(const short8*)(wsw + (((0*6 + nt)*6 + ks)*64 + lane)*8);
                short8 Bt = *(const short8*)(wsw + (((1*6 + nt)*6 + ks)*64 + lane)*8);
                accS[nt] = __builtin_amdgcn_mfma_f32_16x16x32_bf16(aS, Bs, accS[nt], 0, 0, 0);
                accT[nt] = __builtin_amdgcn_mfma_f32_16x16x32_bf16(aT, Bt, accT[nt], 0, 0, 0);
            }
        }

        // epilogue for this ct tile
        #pragma unroll
        for (int nt = 0; nt < 6; ++nt) {
            int p = nt*16 + mrow;
            float fsv = fsL[p];
            float cbv = cbL[p];
            float* og = out + (size_t)b*PREDN*CF + p*CF + (cw<<5) + (ct<<4) + (q<<2);
            f32x4 r;
            #pragma unroll
            for (int r4 = 0; r4 < 4; ++r4)
                r[r4] = fmaf(fsv, accS[nt][r4], accT[nt][r4] + cbv);
            *(f32x4*)og = r;
        }
    }
}

// ---------------------------------------------------------------- launch
extern "C" void kernel_launch(void* const* d_in, const int* in_sizes, int n_in,
                              void* d_out, int out_size, void* d_ws, size_t ws_size,
                              hipStream_t stream)
{
    const float* x        = (const float*)d_in[0];
    const float* decomp_w = (const float*)d_in[1];
    const float* trend_W  = (const float*)d_in[2];
    const float* trend_b  = (const float*)d_in[3];
    const float* seas_W   = (const float*)d_in[4];
    const float* seas_b   = (const float*)d_in[5];
    const float* lagc_W   = (const float*)d_in[6];
    const float* lagc_b   = (const float*)d_in[7];
    const float* res_wx   = (const float*)d_in[8];
    const float* res_wy   = (const float*)d_in[9];
    const float* res_wz   = (const float*)d_in[10];
    const float* ro_W1    = (const float*)d_in[11];
    const float* ro_b1    = (const float*)d_in[12];
    const float* ro_W2    = (const float*)d_in[13];
    const float* ro_b2    = (const float*)d_in[14];
    const float* alpha    = (const float*)d_in[15];
    float* out = (float*)d_out;
    float* ws  = (float*)d_ws;

    k_pre<<<1, 128, 0, stream>>>(decomp_w, res_wx, res_wy, res_wz, ws);
    k_swz<<<144, 256, 0, stream>>>(seas_W, trend_W, alpha, ws);
    k_quantum<<<(BB*3 + 63)/64, 64, 0, stream>>>(x, lagc_W, lagc_b, ws, ws + WS_FEATS);
    k_gemm<<<BB, 128, 0, stream>>>(x, ws, seas_b, trend_b,
                                   ro_W1, ro_b1, ro_W2, ro_b2, alpha, out);
}

// Round 4
// 538.857 us; speedup vs baseline: 1.7359x; 1.3805x over previous
//
#include <hip/hip_runtime.h>
#include <math.h>

#define BB   4096
#define SEQL 168
#define CF   64
#define PREDN 96
#define KK   25
#define NLAG 11
#define LSTR 178            // u16 elements per channel row in LDS (89 dwords, odd -> conflict-free)

// ws layout (float offsets):
// [0,1600)        softmax conv kernels (fp32, [c][25])
// [1600,1888)     Rot unitaries (36 x 8)
// [2048, 51200)   quantum feats (4096 x 12)
// [51200, 69632)  swizzled bf16 weights (36864 u16): [mat][nt6][ks6][lane64][j8]
#define WS_KER   0
#define WS_U     1600
#define WS_FEATS 2048
#define WS_SWZ   51200

typedef __attribute__((ext_vector_type(8))) short short8;
typedef __attribute__((ext_vector_type(4))) float f32x4;

__device__ __forceinline__ unsigned short f2bf(float f) {
    unsigned int u = __float_as_uint(f);
    u = (u + 0x7FFFu + ((u >> 16) & 1u)) >> 16;   // RNE
    return (unsigned short)u;
}

// ---------------------------------------------------------------- precompute (small)
__global__ void k_pre(const float* __restrict__ decomp_w,
                      const float* __restrict__ wx,
                      const float* __restrict__ wy,
                      const float* __restrict__ wz,
                      float* __restrict__ ws)
{
    int tid = threadIdx.x;
    if (tid < 64) {
        float v[KK]; float mx = -1e30f;
        #pragma unroll
        for (int k = 0; k < KK; ++k) { v[k] = decomp_w[tid*KK + k]; mx = fmaxf(mx, v[k]); }
        float s = 0.f;
        #pragma unroll
        for (int k = 0; k < KK; ++k) { v[k] = expf(v[k] - mx); s += v[k]; }
        float inv = 1.f / s;
        #pragma unroll
        for (int k = 0; k < KK; ++k) ws[WS_KER + tid*KK + k] = v[k]*inv;
    } else if (tid < 64 + 36) {
        int i = tid - 64;
        int circ = i / 12, r = i % 12;
        const float* w = (circ == 0) ? wx : (circ == 1 ? wy : wz);
        float phi = w[r*3+0], th = w[r*3+1], om = w[r*3+2];
        float ct = cosf(0.5f*th), st = sinf(0.5f*th);
        float po = 0.5f*(phi+om), pm = 0.5f*(phi-om);
        float cpo = cosf(po), spo = sinf(po);
        float cpm = cosf(pm), spm = sinf(pm);
        float* U = ws + WS_U + i*8;
        U[0] =  cpo*ct; U[1] = -spo*ct;
        U[2] = -cpm*st; U[3] = -spm*st;
        U[4] =  cpm*st; U[5] = -spm*st;
        U[6] =  cpo*ct; U[7] =  spo*ct;
    }
}

// ---------------------------------------------------------------- weight swizzle (parallel)
__global__ void k_swz(const float* __restrict__ sW,
                      const float* __restrict__ tW,
                      const float* __restrict__ alpha,
                      float* __restrict__ ws)
{
    int idx = blockIdx.x * blockDim.x + threadIdx.x;
    if (idx >= 2*6*6*64*8) return;
    float oma = 1.f - 1.f/(1.f + expf(-alpha[0]));
    unsigned short* wsw = (unsigned short*)(ws + WS_SWZ);
    int j    = idx & 7;
    int lane = (idx >> 3) & 63;
    int rem  = idx >> 9;
    int ks   = rem % 6;
    int nt   = (rem / 6) % 6;
    int mat  = rem / 36;
    int p = nt*16 + (lane & 15);
    int l = ks*32 + ((lane >> 4) & 3)*8 + j;
    float v = 0.f;
    if (l < SEQL) v = mat ? oma * tW[p*SEQL + l] : sW[p*SEQL + l];
    wsw[idx] = f2bf(v);
}

// ---------------------------------------------------------------- quantum feats
__global__ void k_quantum(const float* __restrict__ x,
                          const float* __restrict__ lagc_W,
                          const float* __restrict__ lagc_b,
                          const float* __restrict__ ws,
                          float* __restrict__ feats)
{
    int tid = blockIdx.x * blockDim.x + threadIdx.x;
    if (tid >= BB*3) return;
    int b = tid / 3, circ = tid - b*3;

    const int LAGS[NLAG] = {167,166,165,164,163,162,145,144,143,1,0};
    const float* xb = x + (size_t)b*SEQL*CF + (CF-1);
    float lag[NLAG];
    #pragma unroll
    for (int j = 0; j < NLAG; ++j) lag[j] = xb[LAGS[j]*CF];

    float cq[4], sq[4];
    #pragma unroll
    for (int q = 0; q < 4; ++q) {
        float acc = lagc_b[q];
        #pragma unroll
        for (int j = 0; j < NLAG; ++j) acc = fmaf(lag[j], lagc_W[q*NLAG + j], acc);
        float half = 0.5f * 3.14159265358979323846f * tanhf(acc);
        cq[q] = cosf(half); sq[q] = sinf(half);
    }

    float sr[16], si[16];
    #pragma unroll
    for (int i = 0; i < 16; ++i) { sr[i] = 0.f; si[i] = 0.f; }
    sr[0] = 1.f;

    const float* Ub = ws + WS_U + circ*96;

    for (int layer = 0; layer < 3; ++layer) {
        #pragma unroll
        for (int q = 0; q < 4; ++q) {
            int msk = 1 << (3-q);
            float cc = cq[q], ss = sq[q];
            #pragma unroll
            for (int idx = 0; idx < 16; ++idx) {
                if (idx & msk) continue;
                int j = idx | msk;
                float a0r = sr[idx], a0i = si[idx];
                float a1r = sr[j],   a1i = si[j];
                sr[idx] = cc*a0r - ss*a1r;  si[idx] = cc*a0i - ss*a1i;
                sr[j]   = ss*a0r + cc*a1r;  si[j]   = ss*a0i + cc*a1i;
            }
        }
        #pragma unroll
        for (int q = 0; q < 4; ++q) {
            const float* U = Ub + (layer*4 + q)*8;
            float u00r=U[0],u00i=U[1],u01r=U[2],u01i=U[3];
            float u10r=U[4],u10i=U[5],u11r=U[6],u11i=U[7];
            int msk = 1 << (3-q);
            #pragma unroll
            for (int idx = 0; idx < 16; ++idx) {
                if (idx & msk) continue;
                int j = idx | msk;
                float a0r = sr[idx], a0i = si[idx];
                float a1r = sr[j],   a1i = si[j];
                sr[idx] = u00r*a0r - u00i*a0i + u01r*a1r - u01i*a1i;
                si[idx] = u00r*a0i + u00i*a0r + u01r*a1i + u01i*a1r;
                sr[j]   = u10r*a0r - u10i*a0i + u11r*a1r - u11i*a1i;
                si[j]   = u10r*a0i + u10i*a0r + u11r*a1i + u11i*a1r;
            }
        }
        #pragma unroll
        for (int q = 0; q < 4; ++q) {
            int t = (q+1) & 3;
            int cm = 1 << (3-q), tm = 1 << (3-t);
            #pragma unroll
            for (int idx = 0; idx < 16; ++idx) {
                if (!(idx & cm) || (idx & tm)) continue;
                int j = idx | tm;
                float tr = sr[idx]; sr[idx] = sr[j]; sr[j] = tr;
                float ti = si[idx]; si[idx] = si[j]; si[j] = ti;
            }
        }
    }

    #pragma unroll
    for (int q = 0; q < 4; ++q) {
        int msk = 1 << (3-q);
        float v = 0.f;
        if (circ == 0) {
            #pragma unroll
            for (int idx = 0; idx < 16; ++idx) {
                if (idx & msk) continue;
                int j = idx | msk;
                v += sr[idx]*sr[j] + si[idx]*si[j];
            }
            v *= 2.f;
        } else if (circ == 1) {
            #pragma unroll
            for (int idx = 0; idx < 16; ++idx) {
                if (idx & msk) continue;
                int j = idx | msk;
                v += sr[idx]*si[j] - si[idx]*sr[j];
            }
            v *= 2.f;
        } else {
            #pragma unroll
            for (int idx = 0; idx < 16; ++idx) {
                if (idx & msk) continue;
                int j = idx | msk;
                v += sr[idx]*sr[idx] + si[idx]*si[idx]
                   - sr[j]*sr[j]     - si[j]*si[j];
            }
        }
        feats[b*12 + circ*4 + q] = v;
    }
}

// ---------------------------------------------------------------- fused conv+GEMM (MFMA)
// 1 block = 1 batch row, 256 threads = 4 waves.
// Phase A: streaming conv, bf16 T/S written to LDS transposed [c][l] (stride 178).
// Phase B: wave ct handles channels [ct*16, ct*16+16); A-frags via 4x ds_read_b32,
// B-frags from pre-swizzled global table (L2-hot). Register-lean by construction.
__launch_bounds__(256, 3)
__global__ void k_gemm(const float* __restrict__ x,
                       const float* __restrict__ ws,
                       const float* __restrict__ seas_b,
                       const float* __restrict__ trend_b,
                       const float* __restrict__ roW1,
                       const float* __restrict__ rob1,
                       const float* __restrict__ roW2,
                       const float* __restrict__ rob2,
                       const float* __restrict__ alpha,
                       float* __restrict__ out)
{
    __shared__ unsigned short lbuf[2*64*LSTR + 64];   // T | S | slack
    __shared__ float fsL[PREDN];
    __shared__ float cbL[PREDN];

    int b = blockIdx.x;
    int tid = threadIdx.x;

    float a_sig = 1.f / (1.f + expf(-alpha[0]));
    float oma   = 1.f - a_sig;

    // readout MLP -> fs[p], cb[p]
    if (tid < PREDN) {
        const float* f = ws + WS_FEATS + b*12;
        float h[12];
        #pragma unroll
        for (int i = 0; i < 12; ++i) {
            float acc = rob1[i];
            #pragma unroll
            for (int j = 0; j < 12; ++j) acc = fmaf(roW1[i*12+j], f[j], acc);
            h[i] = fmaxf(acc, 0.f);
        }
        float acc = rob2[tid];
        #pragma unroll
        for (int i = 0; i < 12; ++i) acc = fmaf(roW2[tid*12+i], h[i], acc);
        float m   = tanhf(acc);
        float fsv = a_sig * (1.f + m);
        fsL[tid] = fsv;
        cbL[tid] = fsv*seas_b[tid] + oma*trend_b[tid];
    }

    // zero the LDS tail (l in [168,178) for every row, both arrays, + slack):
    // fragment reads touch those slots; B is zero there, values just must be finite.
    for (int i = tid; i < 2*64*10 + 64; i += 256) {
        if (i < 2*64*10) {
            int arr = i / 640;
            int rem = i - arr*640;
            int c   = rem / 10;
            int l   = 168 + rem - c*10;
            lbuf[arr*64*LSTR + c*LSTR + l] = 0;
        } else {
            lbuf[2*64*LSTR + (i - 2*64*10)] = 0;
        }
    }

    // ---- Phase A: conv. thread -> (c = tid&63, seg = tid>>6, l in [seg*42, +42)) ----
    {
        int c   = tid & 63;
        int seg = tid >> 6;
        float cf[KK];
        #pragma unroll
        for (int k = 0; k < KK; ++k) cf[k] = ws[WS_KER + c*KK + k];
        const float* xb = x + (size_t)b*SEQL*CF;
        unsigned short* lT = lbuf + c*LSTR;
        unsigned short* lS = lbuf + 64*LSTR + c*LSTR;

        int l0 = seg*42;
        for (int l = l0; l < l0 + 42; ++l) {
            float acc = 0.f, v12;
            if (l >= 12 && l <= SEQL-13) {          // wave-uniform branch
                const float* bp = xb + (l-12)*CF + c;
                #pragma unroll
                for (int k = 0; k < KK; ++k) acc = fmaf(cf[k], bp[k*CF], acc);
                v12 = bp[12*CF];
            } else {
                #pragma unroll
                for (int k = 0; k < KK; ++k) {
                    int ix = l + k - 12;
                    ix = ix < 0 ? 0 : (ix > SEQL-1 ? SEQL-1 : ix);
                    acc = fmaf(cf[k], xb[ix*CF + c], acc);
                }
                v12 = xb[l*CF + c];
            }
            lT[l] = f2bf(acc);
            lS[l] = f2bf(v12 - acc);
        }
    }
    __syncthreads();

    // ---- Phase B: MFMA GEMM ----
    int lane = tid & 63;
    int ct   = tid >> 6;          // wave id = 16-channel tile
    int mrow = lane & 15;
    int q    = lane >> 4;
    int c    = ct*16 + mrow;

    const unsigned int* L32 = (const unsigned int*)lbuf;
    const int SOFF = 64*LSTR/2;   // dword offset of S array
    const unsigned short* wsw = (const unsigned short*)(ws + WS_SWZ);

    f32x4 accS[6], accT[6];
    #pragma unroll
    for (int nt = 0; nt < 6; ++nt) {
        accS[nt] = (f32x4){0.f,0.f,0.f,0.f};
        accT[nt] = (f32x4){0.f,0.f,0.f,0.f};
    }

    for (int ks = 0; ks < 6; ++ks) {
        int ai = c*(LSTR/2) + ks*16 + q*4;        // dword index of fragment start
        union { unsigned int u[4]; short8 v; } ut, us;
        #pragma unroll
        for (int d = 0; d < 4; ++d) {
            ut.u[d] = L32[ai + d];
            us.u[d] = L32[SOFF + ai + d];
        }
        short8 aT = ut.v, aS = us.v;
        #pragma unroll
        for (int nt = 0; nt < 6; ++nt) {
            short8 Bs = *(const short8*)(wsw + (((0*6 + nt)*6 + ks)*64 + lane)*8);
            short8 Bt = *(const short8*)(wsw + (((1*6 + nt)*6 + ks)*64 + lane)*8);
            accS[nt] = __builtin_amdgcn_mfma_f32_16x16x32_bf16(aS, Bs, accS[nt], 0, 0, 0);
            accT[nt] = __builtin_amdgcn_mfma_f32_16x16x32_bf16(aT, Bt, accT[nt], 0, 0, 0);
        }
    }

    // epilogue: C/D col = lane&15 = p-within-tile, row = q*4+reg = c-within-tile
    #pragma unroll
    for (int nt = 0; nt < 6; ++nt) {
        int p = nt*16 + mrow;
        float fsv = fsL[p];
        float cbv = cbL[p];
        float* og = out + (size_t)b*PREDN*CF + p*CF + ct*16 + (q<<2);
        f32x4 r;
        #pragma unroll
        for (int r4 = 0; r4 < 4; ++r4)
            r[r4] = fmaf(fsv, accS[nt][r4], accT[nt][r4] + cbv);
        *(f32x4*)og = r;
    }
}

// ---------------------------------------------------------------- launch
extern "C" void kernel_launch(void* const* d_in, const int* in_sizes, int n_in,
                              void* d_out, int out_size, void* d_ws, size_t ws_size,
                              hipStream_t stream)
{
    const float* x        = (const float*)d_in[0];
    const float* decomp_w = (const float*)d_in[1];
    const float* trend_W  = (const float*)d_in[2];
    const float* trend_b  = (const float*)d_in[3];
    const float* seas_W   = (const float*)d_in[4];
    const float* seas_b   = (const float*)d_in[5];
    const float* lagc_W   = (const float*)d_in[6];
    const float* lagc_b   = (const float*)d_in[7];
    const float* res_wx   = (const float*)d_in[8];
    const float* res_wy   = (const float*)d_in[9];
    const float* res_wz   = (const float*)d_in[10];
    const float* ro_W1    = (const float*)d_in[11];
    const float* ro_b1    = (const float*)d_in[12];
    const float* ro_W2    = (const float*)d_in[13];
    const float* ro_b2    = (const float*)d_in[14];
    const float* alpha    = (const float*)d_in[15];
    float* out = (float*)d_out;
    float* ws  = (float*)d_ws;

    k_pre<<<1, 128, 0, stream>>>(decomp_w, res_wx, res_wy, res_wz, ws);
    k_swz<<<144, 256, 0, stream>>>(seas_W, trend_W, alpha, ws);
    k_quantum<<<(BB*3 + 63)/64, 64, 0, stream>>>(x, lagc_W, lagc_b, ws, ws + WS_FEATS);
    k_gemm<<<BB, 256, 0, stream>>>(x, ws, seas_b, trend_b,
                                   ro_W1, ro_b1, ro_W2, ro_b2, alpha, out);
}